// Round 10
// baseline (145.052 us; speedup 1.0000x reference)
//
#include <hip/hip_runtime.h>

#define N_NODES_C   524288
#define N_EDGES_C   786432
#define NUM_GRAPHS_C 8192
#define NT 16          // NUM_NODE_TYPES
#define NODE_DIM_C 256
#define EDGE_DIM_C 128
#define HDIM 384       // NODE_DIM + EDGE_DIM
#define KC 48          // folded inner dim: 16 (node) + 32 (edge)

// R20 = R19 (measured best, 139.6 us) + ONE change: k0 removed.
//  - kr's 2048x256 grid covers N_NODES exactly -> per-thread node boundary
//    detect writes nstart (k0's node half, same code).
//  - kr's edge bounds via R0-verified in-wave dual bsearch (lanes 0-31 chase
//    start, 32-63 chase end; 20 L2-hit rounds amortized over 8192 waves).
//  - kr writes ecnt[g] for k3's normalize (estart array gone).
// Everything else verbatim from R19:
//  - km: fold(72) + slice-aligned node means(2048) + edge gather(16384);
//    slice = idx>>16; blk%8 == slice == XCD heuristic (correctness-indep);
//    ONE int4 desc load per edge wave; em8 slice-major plain stores (NO
//    global atomics).
//  - k3: fold 8 slice partials + normalize + fused MLP.
#define FOLD_BLOCKS 72             // ceil(KC*HDIM/256)
#define NODE_BLOCKS 2048           // slice-aligned: r&7 = slice octant
#define EDGE_BLOCKS 16384          // wave = (graph, slice); blk%8 = slice
#define NODE_BASE   FOLD_BLOCKS    // 72 % 8 == 0
#define EDGE_BASE   (FOLD_BLOCKS + NODE_BLOCKS)   // 2120 % 8 == 0
#define TOTAL_BLOCKS (FOLD_BLOCKS + NODE_BLOCKS + EDGE_BLOCKS)

// ---------------- workspace layout (bytes, 64-aligned) ----------------
#define WS_NM    0                  // float[8192*16]        512 KB
#define WS_EM8   524288             // float[8][8192][32]    8 MB (slice-major)
#define WS_WC    8912896            // float[48*384]         73728 B
#define WS_NS    8986624            // int[8193]
#define WS_ECNT  9019456            // int[8192]
#define WS_DESC  9052288            // int4[8192*8]          1 MB (graph-major)
#define WS_REC   10100864           // int[1572864]          6 MB

__device__ __forceinline__ void f4_add(float4& a, const float4 v) {
    a.x += v.x; a.y += v.y; a.z += v.z; a.w += v.w;
}

__device__ __forceinline__ void f4_shfl_xor_add(float4& a, int mask) {
    a.x += __shfl_xor(a.x, mask, 64);
    a.y += __shfl_xor(a.y, mask, 64);
    a.z += __shfl_xor(a.z, mask, 64);
    a.w += __shfl_xor(a.w, mask, 64);
}

__device__ __forceinline__ int lower_bound_i32(const int* __restrict__ a, int n, int key) {
    int lo = 0, hi = n;
    while (lo < hi) {
        int mid = (lo + hi) >> 1;
        if (a[mid] < key) lo = mid + 1; else hi = mid;
    }
    return lo;
}

// In-wave segment bounds: lanes 0-31 chase start(g), lanes 32-63 chase end(g)
// concurrently, then shuffle-broadcast (R0-verified).
__device__ __forceinline__ void wave_seg_bounds(const int* __restrict__ b, int n,
                                                int g, int lane, int& s, int& e) {
    int key = g + ((lane >= 32) ? 1 : 0);
    int lo = lower_bound_i32(b, n, key);
    s = __shfl(lo, 0, 64);
    e = __shfl(lo, 32, 64);
}

// kr: fused prep, 2048 blocks x 256 (grid == N_NODES threads exactly).
//  - thread i: node boundary detect -> nstart (bnode sorted).
//  - wave w: graph g = blk*4+w; in-wave dual bsearch of bedge -> (s,e);
//    ecnt[g] = e-s; LDS histogram into 16 (slice,endpoint) bins; in-wave
//    scan; desc int4 per slice {src_start, dst_start, dst_end, cnt};
//    LDS-cursor record placement into graph-private region [2s,2e) of rec.
//  No global atomics.
__global__ __launch_bounds__(256) void kr_build(
    const int* __restrict__ bnode, const int* __restrict__ bedge,
    const int* __restrict__ esrc, const int* __restrict__ edst,
    int* __restrict__ rec, int4* __restrict__ desc,
    int* __restrict__ ecnt, int* __restrict__ nstart) {
    int tid = threadIdx.x, blk = blockIdx.x;
    int i = blk * 256 + tid;
    {   // node segment bounds (2048*256 threads cover N_NODES exactly)
        int g0 = bnode[i];
        int hi = (i + 1 < N_NODES_C) ? bnode[i + 1] : NUM_GRAPHS_C;
        if (i == 0) for (int g = 0; g <= g0; ++g) nstart[g] = 0;
        for (int g = g0 + 1; g <= hi; ++g) nstart[g] = i + 1;
    }

    int wave = tid >> 6, lane = tid & 63;
    int g = blk * 4 + wave;
    int s, e;
    wave_seg_bounds(bedge, N_EDGES_C, g, lane, s, e);
    int cnt = e - s;
    if (lane == 0) ecnt[g] = cnt;

    __shared__ int lcnt[4][16];
    __shared__ int lcur[4][16];
    if (lane < 16) lcnt[wave][lane] = 0;      // wave-lockstep DS ordering
    for (int q = s + lane; q < e; q += 64) {
        int a = esrc[q];
        atomicAdd(&lcnt[wave][((a >> 16) << 1) + 0], 1);
        int b = edst[q];
        atomicAdd(&lcnt[wave][((b >> 16) << 1) + 1], 1);
    }
    int c = (lane < 16) ? lcnt[wave][lane] : 0;
    int incl = c;
    #pragma unroll
    for (int d = 1; d < 16; d <<= 1) {
        int v = __shfl_up(incl, d, 64);
        if (lane >= d) incl += v;
    }
    int excl = incl - c;
    if (lane < 16) lcur[wave][lane] = excl;   // local cursor
    // desc[(g,slice)] = {src_start, dst_start, dst_end, cnt} (absolute)
    int i0 = (lane < 8) ? 2 * lane : 0;
    int i1 = (lane < 8) ? 2 * lane + 1 : 0;
    int i2 = (lane < 7) ? 2 * lane + 2 : 0;
    int b0 = __shfl(excl, i0, 64);
    int b1 = __shfl(excl, i1, 64);
    int e1 = __shfl(excl, i2, 64);
    if (lane < 8) {
        int e1a = (lane == 7) ? 2 * s + 2 * cnt : 2 * s + e1;
        desc[(g << 3) + lane] = make_int4(2 * s + b0, 2 * s + b1, e1a, cnt);
    }
    for (int q = s + lane; q < e; q += 64) {
        int a = esrc[q];
        int pa = atomicAdd(&lcur[wave][((a >> 16) << 1) + 0], 1);
        rec[2 * s + pa] = a;
        int b = edst[q];
        int pb = atomicAdd(&lcur[wave][((b >> 16) << 1) + 1], 1);
        rec[2 * s + pb] = b;
    }
}

// KM mega-kernel:
//  blocks [0,72):             Wc fold: Wc[k][j] = embedder_row(k) . W1 col j.
//  blocks [NODE_BASE,+2048):  node means; r&7 = slice octant (g>>10) so the
//     sequential h_node stream primes the owning XCD's L2.
//  blocks [EDGE_BASE,+16384): edge partials; wave = (g, slice); bounds from
//     ONE int4 desc load; rows L2-local; plain float4 store to em8[slice][g].
__global__ __launch_bounds__(256) void km_mega(
    const float* __restrict__ h_node,
    const int* __restrict__ nstart, const int4* __restrict__ desc,
    const int* __restrict__ rec,
    const float* __restrict__ Wn, const float* __restrict__ We,
    const float* __restrict__ W1,
    float* __restrict__ nm, float* __restrict__ em8, float* __restrict__ Wc) {
    int blk  = blockIdx.x;
    int wave = threadIdx.x >> 6;
    int lane = threadIdx.x & 63;
    const float4* h4 = (const float4*)h_node;
    const float4 z4 = make_float4(0.f, 0.f, 0.f, 0.f);

    if (blk < FOLD_BLOCKS) {
        // ---- weight fold ----
        int o = blk * 256 + threadIdx.x;        // 0..18431 (= KC*HDIM)
        if (o >= KC * HDIM) return;
        int k = o / HDIM, j = o % HDIM;
        float acc = 0.f;
        if (k < NT) {
            const float* wr = &Wn[k * NODE_DIM_C];
            #pragma unroll 16
            for (int kk = 0; kk < NODE_DIM_C; ++kk)
                acc = fmaf(wr[kk], W1[(size_t)kk * HDIM + j], acc);
        } else {
            const float* wr = &We[(k - NT) * EDGE_DIM_C];
            #pragma unroll 16
            for (int kk = 0; kk < EDGE_DIM_C; ++kk)
                acc = fmaf(wr[kk], W1[(size_t)(NODE_DIM_C + kk) * HDIM + j], acc);
        }
        Wc[o] = acc;
    } else if (blk < EDGE_BASE) {
        // ---- node means (slice-aligned placement) ----
        int r = blk - NODE_BASE;
        int s8 = r & 7;                 // target XCD == slice octant
        int g  = s8 * 1024 + (r >> 3) * 4 + wave;
        int s = nstart[g], e = nstart[g + 1];
        int row_off = lane >> 2;   // 0..15
        int quad    = lane & 3;    // 0..3
        float4 a0 = z4, a1 = z4;
        int i = s + row_off;
        for (; i + 16 < e; i += 32) {
            float4 v0 = h4[(size_t)i * 4 + quad];
            float4 v1 = h4[(size_t)(i + 16) * 4 + quad];
            f4_add(a0, v0);
            f4_add(a1, v1);
        }
        if (i < e) f4_add(a0, h4[(size_t)i * 4 + quad]);
        f4_add(a0, a1);
        f4_shfl_xor_add(a0, 4);
        f4_shfl_xor_add(a0, 8);
        f4_shfl_xor_add(a0, 16);
        f4_shfl_xor_add(a0, 32);
        if (row_off == 0) {
            float inv = 1.f / fmaxf((float)(e - s), 1.f);
            ((float4*)nm)[(size_t)g * 4 + quad] =
                make_float4(a0.x * inv, a0.y * inv, a0.z * inv, a0.w * inv);
        }
    } else {
        // ---- edge partial sums (compacted slice-local gather) ----
        int r     = blk - EDGE_BASE;
        int slice = r & 7;                      // == blk%8 == XCD (heuristic)
        int g     = (r >> 3) * 4 + wave;
        int4 d    = desc[(g << 3) + slice];     // ONE load: {s0, s1, e1, cnt}
        int slot = lane >> 3;          // 0..7 record slot
        int p    = (lane >> 2) & 1;    // 0=src 1=dst
        int quad = lane & 3;           // 16 B quarter of the 64-B row
        int st = p ? d.y : d.x;
        int en = p ? d.z : d.y;
        int cmax = max(d.y - d.x, d.z - d.y);
        int T = (cmax + 7) >> 3;       // wave-uniform trips, 8 recs/list/iter
        float4 acc = z4;
        int i = st + slot;
        int idx = (i < en) ? rec[i] : -1;
        for (int t = 1; t < T; ++t) {
            int i2 = i + 8;
            int nx = (i2 < en) ? rec[i2] : -1;   // prefetch next record
            if (idx >= 0) f4_add(acc, h4[(size_t)idx * 4 + quad]);
            idx = nx; i = i2;
        }
        if (idx >= 0) f4_add(acc, h4[(size_t)idx * 4 + quad]);
        // reduce over slot (lane bits 3..5)
        f4_shfl_xor_add(acc, 8);
        f4_shfl_xor_add(acc, 16);
        f4_shfl_xor_add(acc, 32);
        if (slot == 0) {
            // em8[slice][g] row = 32 floats: quads 0..3 src half, 4..7 dst half
            ((float4*)em8)[((size_t)(slice * NUM_GRAPHS_C + g)) * 8 + p * 4 + quad] = acc;
        }
    }
}

// K3: fused MLP.  f[g] = [nm(g) | (Σ_s em8[s][g]) / ecnt(g)]  (48 dims)
// pred[g] = relu(f[g] @ Wc + b1) . W2 + b2
#define GPB 16
__global__ __launch_bounds__(HDIM) void k3_mlp(
    const float* __restrict__ nm, const float* __restrict__ em8,
    const int* __restrict__ ecnt,
    const float* __restrict__ Wc, const float* __restrict__ b1,
    const float* __restrict__ W2, const float* __restrict__ b2,
    float* __restrict__ pred) {
    int j = threadIdx.x;
    float wc[KC];
    #pragma unroll
    for (int k = 0; k < KC; ++k) wc[k] = Wc[k * HDIM + j];
    float b1j = b1[j], w2j = W2[j], b20 = b2[0];

    __shared__ float fs[GPB][KC];
    __shared__ float part[GPB][6];
    int g0 = blockIdx.x * GPB;
    for (int t = j; t < GPB * KC; t += HDIM) {
        int g = t / KC, k = t % KC;
        int G = g0 + g;
        float val;
        if (k < NT) {
            val = nm[(size_t)G * NT + k];
        } else {
            float ssum = 0.f;
            #pragma unroll
            for (int s = 0; s < 8; ++s)
                ssum += em8[((size_t)(s * NUM_GRAPHS_C + G)) * 32 + (k - NT)];
            val = ssum / fmaxf((float)ecnt[G], 1.f);
        }
        fs[g][k] = val;
    }
    __syncthreads();

    int wave = j >> 6, lane = j & 63;
    for (int g = 0; g < GPB; ++g) {
        float z = b1j;
        #pragma unroll
        for (int k = 0; k < KC; ++k) z = fmaf(fs[g][k], wc[k], z);
        z = fmaxf(z, 0.f);
        float p = z * w2j;
        #pragma unroll
        for (int off = 32; off > 0; off >>= 1) p += __shfl_down(p, off, 64);
        if (lane == 0) part[g][wave] = p;
    }
    __syncthreads();
    if (j < GPB) {
        float sacc = b20;
        #pragma unroll
        for (int w = 0; w < 6; ++w) sacc += part[j][w];
        pred[g0 + j] = sacc;
    }
}

extern "C" void kernel_launch(void* const* d_in, const int* in_sizes, int n_in,
                              void* d_out, int out_size, void* d_ws, size_t ws_size,
                              hipStream_t stream) {
    const float* h_node     = (const float*)d_in[0];
    // d_in[1] = pos_node (unused)
    const int*   batch_node = (const int*)d_in[2];
    const int*   edge_index = (const int*)d_in[3];   // [2, E] row-major
    const int*   batch_edge = (const int*)d_in[4];
    const float* W_node     = (const float*)d_in[5];
    const float* W_edge     = (const float*)d_in[6];
    const float* W1         = (const float*)d_in[7];
    const float* b1         = (const float*)d_in[8];
    const float* W2         = (const float*)d_in[9];
    const float* b2         = (const float*)d_in[10];
    float* pred = (float*)d_out;

    char* ws = (char*)d_ws;
    float* nm     = (float*)(ws + WS_NM);
    float* em8    = (float*)(ws + WS_EM8);
    float* Wc     = (float*)(ws + WS_WC);
    int*   nstart = (int*)(ws + WS_NS);
    int*   ecnt   = (int*)(ws + WS_ECNT);
    int4*  desc   = (int4*)(ws + WS_DESC);
    int*   rec    = (int*)(ws + WS_REC);

    const int* esrc = edge_index;
    const int* edst = edge_index + N_EDGES_C;

    // kr: fused prep (node bounds + in-wave edge bsearch + records + desc)
    kr_build<<<NUM_GRAPHS_C / 4, 256, 0, stream>>>(
        batch_node, batch_edge, esrc, edst, rec, desc, ecnt, nstart);
    // KM: fold (72) + slice-aligned node means (2048) + compacted edge gather (16384)
    km_mega <<<TOTAL_BLOCKS, 256, 0, stream>>>(
        h_node, nstart, desc, rec, W_node, W_edge, W1, nm, em8, Wc);
    // K3: fold partials + normalize + MLP
    k3_mlp  <<<NUM_GRAPHS_C / GPB, HDIM, 0, stream>>>(
        nm, em8, ecnt, Wc, b1, W2, b2, pred);
}

// Round 11
// 142.225 us; speedup vs baseline: 1.0199x; 1.0199x over previous
//
#include <hip/hip_runtime.h>

#define N_NODES_C   524288
#define N_EDGES_C   786432
#define NUM_GRAPHS_C 8192
#define NT 16          // NUM_NODE_TYPES
#define NODE_DIM_C 256
#define EDGE_DIM_C 128
#define HDIM 384       // NODE_DIM + EDGE_DIM
#define KC 48          // folded inner dim: 16 (node) + 32 (edge)

// R21 = R19 verbatim (measured best, 139.6 us). R20's k0-removal REVERTED:
// k0's sequential bedge/bnode stream is a cheap bounds pass AND an L2
// prefetch for kr; replacing it with per-wave dependent bsearch put 20
// serial cold-memory rounds on every kr wave's critical path (145.1 us).
// Lesson (R18, R20): fusions that lengthen the per-wave serial chain lose,
// even when they remove a pass/launch.
// Proven pieces:
//  - k0: boundary-detect segment bounds (no atomics), primes index arrays
//  - kr: per-graph record compaction, LDS-only atomics; desc int4 per
//    (g,slice) = {src_start, dst_start, dst_end, cnt}
//  - km: fold(72) + slice-aligned node means(2048) + edge gather(16384);
//    slice = idx>>16; blk%8 == slice == XCD heuristic (correctness-indep);
//    ONE int4 desc load per edge wave (R19's isolated win, -4 us);
//    em8 slice-major plain stores (NO global atomics — R15 lesson)
//  - k3: fold 8 slice partials + normalize + fused MLP
#define FOLD_BLOCKS 72             // ceil(KC*HDIM/256)
#define NODE_BLOCKS 2048           // slice-aligned: r&7 = slice octant
#define EDGE_BLOCKS 16384          // wave = (graph, slice); blk%8 = slice
#define NODE_BASE   FOLD_BLOCKS    // 72 % 8 == 0
#define EDGE_BASE   (FOLD_BLOCKS + NODE_BLOCKS)   // 2120 % 8 == 0
#define TOTAL_BLOCKS (FOLD_BLOCKS + NODE_BLOCKS + EDGE_BLOCKS)

// ---------------- workspace layout (bytes, 64-aligned) ----------------
#define WS_NM    0                  // float[8192*16]        512 KB
#define WS_EM8   524288             // float[8][8192][32]    8 MB (slice-major)
#define WS_WC    8912896            // float[48*384]         73728 B
#define WS_ES    8986624            // int[8193]
#define WS_NS    9019456            // int[8193]
#define WS_DESC  9052288            // int4[8192*8]          1 MB (graph-major)
#define WS_REC   10100864           // int[1572864]          6 MB

__device__ __forceinline__ void f4_add(float4& a, const float4 v) {
    a.x += v.x; a.y += v.y; a.z += v.z; a.w += v.w;
}

__device__ __forceinline__ void f4_shfl_xor_add(float4& a, int mask) {
    a.x += __shfl_xor(a.x, mask, 64);
    a.y += __shfl_xor(a.y, mask, 64);
    a.z += __shfl_xor(a.z, mask, 64);
    a.w += __shfl_xor(a.w, mask, 64);
}

// k0: segment starts via boundary detection (batch arrays are sorted).
// estart[g] = first i with bedge[i] >= g; estart[NUM_GRAPHS] = E. Same for nodes.
__global__ __launch_bounds__(256) void k0_prep(
    const int* __restrict__ bnode, const int* __restrict__ bedge,
    int* __restrict__ estart, int* __restrict__ nstart) {
    int i = blockIdx.x * 256 + threadIdx.x;
    if (i < N_EDGES_C) {
        int g0 = bedge[i];
        int hi = (i + 1 < N_EDGES_C) ? bedge[i + 1] : NUM_GRAPHS_C;
        if (i == 0) for (int g = 0; g <= g0; ++g) estart[g] = 0;
        for (int g = g0 + 1; g <= hi; ++g) estart[g] = i + 1;
    }
    if (i < N_NODES_C) {
        int g0 = bnode[i];
        int hi = (i + 1 < N_NODES_C) ? bnode[i + 1] : NUM_GRAPHS_C;
        if (i == 0) for (int g = 0; g <= g0; ++g) nstart[g] = 0;
        for (int g = g0 + 1; g <= hi; ++g) nstart[g] = i + 1;
    }
}

// kr: per-graph record build, one wave per graph, LDS-only atomics.
// Pass 1: histogram the graph's ~96 edges into 16 (slice,endpoint) bins.
// In-wave scan of 16 counts -> desc int4 per slice {src_start, dst_start,
// dst_end, cnt} (absolute record offsets) + LDS cursors.
// Pass 2: place each endpoint's node index at its bin cursor (graph-private
// region [2s,2e) of rec).
__global__ __launch_bounds__(256) void kr_build(
    const int* __restrict__ esrc, const int* __restrict__ edst,
    const int* __restrict__ estart,
    int* __restrict__ rec, int4* __restrict__ desc) {
    int wave = threadIdx.x >> 6, lane = threadIdx.x & 63;
    int g = blockIdx.x * 4 + wave;
    int s = estart[g], e = estart[g + 1];
    int cnt = e - s;
    __shared__ int lcnt[4][16];
    __shared__ int lcur[4][16];
    if (lane < 16) lcnt[wave][lane] = 0;      // wave-lockstep DS ordering
    for (int i = s + lane; i < e; i += 64) {
        int a = esrc[i];
        atomicAdd(&lcnt[wave][((a >> 16) << 1) + 0], 1);
        int b = edst[i];
        atomicAdd(&lcnt[wave][((b >> 16) << 1) + 1], 1);
    }
    int c = (lane < 16) ? lcnt[wave][lane] : 0;
    int incl = c;
    #pragma unroll
    for (int d = 1; d < 16; d <<= 1) {
        int v = __shfl_up(incl, d, 64);
        if (lane >= d) incl += v;
    }
    int excl = incl - c;
    if (lane < 16) lcur[wave][lane] = excl;   // local cursor
    // desc[(g,slice)] = {src_start, dst_start, dst_end, cnt} (absolute)
    int i0 = (lane < 8) ? 2 * lane : 0;
    int i1 = (lane < 8) ? 2 * lane + 1 : 0;
    int i2 = (lane < 7) ? 2 * lane + 2 : 0;
    int b0 = __shfl(excl, i0, 64);
    int b1 = __shfl(excl, i1, 64);
    int e1 = __shfl(excl, i2, 64);
    if (lane < 8) {
        int e1a = (lane == 7) ? 2 * s + 2 * cnt : 2 * s + e1;
        desc[(g << 3) + lane] = make_int4(2 * s + b0, 2 * s + b1, e1a, cnt);
    }
    for (int i = s + lane; i < e; i += 64) {
        int a = esrc[i];
        int pa = atomicAdd(&lcur[wave][((a >> 16) << 1) + 0], 1);
        rec[2 * s + pa] = a;
        int b = edst[i];
        int pb = atomicAdd(&lcur[wave][((b >> 16) << 1) + 1], 1);
        rec[2 * s + pb] = b;
    }
}

// KM mega-kernel:
//  blocks [0,72):             Wc fold: Wc[k][j] = embedder_row(k) . W1 col j.
//  blocks [NODE_BASE,+2048):  node means; r&7 = slice octant (g>>10) so the
//     sequential h_node stream primes the owning XCD's L2.
//  blocks [EDGE_BASE,+16384): edge partials; wave = (g, slice); bounds from
//     ONE int4 desc load; rows L2-local; plain float4 store to em8[slice][g].
__global__ __launch_bounds__(256) void km_mega(
    const float* __restrict__ h_node,
    const int* __restrict__ nstart, const int4* __restrict__ desc,
    const int* __restrict__ rec,
    const float* __restrict__ Wn, const float* __restrict__ We,
    const float* __restrict__ W1,
    float* __restrict__ nm, float* __restrict__ em8, float* __restrict__ Wc) {
    int blk  = blockIdx.x;
    int wave = threadIdx.x >> 6;
    int lane = threadIdx.x & 63;
    const float4* h4 = (const float4*)h_node;
    const float4 z4 = make_float4(0.f, 0.f, 0.f, 0.f);

    if (blk < FOLD_BLOCKS) {
        // ---- weight fold ----
        int o = blk * 256 + threadIdx.x;        // 0..18431 (= KC*HDIM)
        if (o >= KC * HDIM) return;
        int k = o / HDIM, j = o % HDIM;
        float acc = 0.f;
        if (k < NT) {
            const float* wr = &Wn[k * NODE_DIM_C];
            #pragma unroll 16
            for (int kk = 0; kk < NODE_DIM_C; ++kk)
                acc = fmaf(wr[kk], W1[(size_t)kk * HDIM + j], acc);
        } else {
            const float* wr = &We[(k - NT) * EDGE_DIM_C];
            #pragma unroll 16
            for (int kk = 0; kk < EDGE_DIM_C; ++kk)
                acc = fmaf(wr[kk], W1[(size_t)(NODE_DIM_C + kk) * HDIM + j], acc);
        }
        Wc[o] = acc;
    } else if (blk < EDGE_BASE) {
        // ---- node means (slice-aligned placement) ----
        int r = blk - NODE_BASE;
        int s8 = r & 7;                 // target XCD == slice octant
        int g  = s8 * 1024 + (r >> 3) * 4 + wave;
        int s = nstart[g], e = nstart[g + 1];
        int row_off = lane >> 2;   // 0..15
        int quad    = lane & 3;    // 0..3
        float4 a0 = z4, a1 = z4;
        int i = s + row_off;
        for (; i + 16 < e; i += 32) {
            float4 v0 = h4[(size_t)i * 4 + quad];
            float4 v1 = h4[(size_t)(i + 16) * 4 + quad];
            f4_add(a0, v0);
            f4_add(a1, v1);
        }
        if (i < e) f4_add(a0, h4[(size_t)i * 4 + quad]);
        f4_add(a0, a1);
        f4_shfl_xor_add(a0, 4);
        f4_shfl_xor_add(a0, 8);
        f4_shfl_xor_add(a0, 16);
        f4_shfl_xor_add(a0, 32);
        if (row_off == 0) {
            float inv = 1.f / fmaxf((float)(e - s), 1.f);
            ((float4*)nm)[(size_t)g * 4 + quad] =
                make_float4(a0.x * inv, a0.y * inv, a0.z * inv, a0.w * inv);
        }
    } else {
        // ---- edge partial sums (compacted slice-local gather) ----
        int r     = blk - EDGE_BASE;
        int slice = r & 7;                      // == blk%8 == XCD (heuristic)
        int g     = (r >> 3) * 4 + wave;
        int4 d    = desc[(g << 3) + slice];     // ONE load: {s0, s1, e1, cnt}
        int slot = lane >> 3;          // 0..7 record slot
        int p    = (lane >> 2) & 1;    // 0=src 1=dst
        int quad = lane & 3;           // 16 B quarter of the 64-B row
        int st = p ? d.y : d.x;
        int en = p ? d.z : d.y;
        int cmax = max(d.y - d.x, d.z - d.y);
        int T = (cmax + 7) >> 3;       // wave-uniform trips, 8 recs/list/iter
        float4 acc = z4;
        int i = st + slot;
        int idx = (i < en) ? rec[i] : -1;
        for (int t = 1; t < T; ++t) {
            int i2 = i + 8;
            int nx = (i2 < en) ? rec[i2] : -1;   // prefetch next record
            if (idx >= 0) f4_add(acc, h4[(size_t)idx * 4 + quad]);
            idx = nx; i = i2;
        }
        if (idx >= 0) f4_add(acc, h4[(size_t)idx * 4 + quad]);
        // reduce over slot (lane bits 3..5)
        f4_shfl_xor_add(acc, 8);
        f4_shfl_xor_add(acc, 16);
        f4_shfl_xor_add(acc, 32);
        if (slot == 0) {
            // em8[slice][g] row = 32 floats: quads 0..3 src half, 4..7 dst half
            ((float4*)em8)[((size_t)(slice * NUM_GRAPHS_C + g)) * 8 + p * 4 + quad] = acc;
        }
    }
}

// K3: fused MLP.  f[g] = [nm(g) | (Σ_s em8[s][g]) / ecnt(g)]  (48 dims)
// pred[g] = relu(f[g] @ Wc + b1) . W2 + b2
#define GPB 16
__global__ __launch_bounds__(HDIM) void k3_mlp(
    const float* __restrict__ nm, const float* __restrict__ em8,
    const int* __restrict__ estart,
    const float* __restrict__ Wc, const float* __restrict__ b1,
    const float* __restrict__ W2, const float* __restrict__ b2,
    float* __restrict__ pred) {
    int j = threadIdx.x;
    float wc[KC];
    #pragma unroll
    for (int k = 0; k < KC; ++k) wc[k] = Wc[k * HDIM + j];
    float b1j = b1[j], w2j = W2[j], b20 = b2[0];

    __shared__ float fs[GPB][KC];
    __shared__ float part[GPB][6];
    int g0 = blockIdx.x * GPB;
    for (int t = j; t < GPB * KC; t += HDIM) {
        int g = t / KC, k = t % KC;
        int G = g0 + g;
        float val;
        if (k < NT) {
            val = nm[(size_t)G * NT + k];
        } else {
            float ssum = 0.f;
            #pragma unroll
            for (int s = 0; s < 8; ++s)
                ssum += em8[((size_t)(s * NUM_GRAPHS_C + G)) * 32 + (k - NT)];
            float ec = (float)(estart[G + 1] - estart[G]);
            val = ssum / fmaxf(ec, 1.f);
        }
        fs[g][k] = val;
    }
    __syncthreads();

    int wave = j >> 6, lane = j & 63;
    for (int g = 0; g < GPB; ++g) {
        float z = b1j;
        #pragma unroll
        for (int k = 0; k < KC; ++k) z = fmaf(fs[g][k], wc[k], z);
        z = fmaxf(z, 0.f);
        float p = z * w2j;
        #pragma unroll
        for (int off = 32; off > 0; off >>= 1) p += __shfl_down(p, off, 64);
        if (lane == 0) part[g][wave] = p;
    }
    __syncthreads();
    if (j < GPB) {
        float sacc = b20;
        #pragma unroll
        for (int w = 0; w < 6; ++w) sacc += part[j][w];
        pred[g0 + j] = sacc;
    }
}

extern "C" void kernel_launch(void* const* d_in, const int* in_sizes, int n_in,
                              void* d_out, int out_size, void* d_ws, size_t ws_size,
                              hipStream_t stream) {
    const float* h_node     = (const float*)d_in[0];
    // d_in[1] = pos_node (unused)
    const int*   batch_node = (const int*)d_in[2];
    const int*   edge_index = (const int*)d_in[3];   // [2, E] row-major
    const int*   batch_edge = (const int*)d_in[4];
    const float* W_node     = (const float*)d_in[5];
    const float* W_edge     = (const float*)d_in[6];
    const float* W1         = (const float*)d_in[7];
    const float* b1         = (const float*)d_in[8];
    const float* W2         = (const float*)d_in[9];
    const float* b2         = (const float*)d_in[10];
    float* pred = (float*)d_out;

    char* ws = (char*)d_ws;
    float* nm     = (float*)(ws + WS_NM);
    float* em8    = (float*)(ws + WS_EM8);
    float* Wc     = (float*)(ws + WS_WC);
    int*   estart = (int*)(ws + WS_ES);
    int*   nstart = (int*)(ws + WS_NS);
    int4*  desc   = (int4*)(ws + WS_DESC);
    int*   rec    = (int*)(ws + WS_REC);

    const int* esrc = edge_index;
    const int* edst = edge_index + N_EDGES_C;

    // k0: segment bounds (no atomics) + L2-prime of index arrays for kr
    k0_prep <<<3072, 256, 0, stream>>>(batch_node, batch_edge, estart, nstart);
    // kr: per-graph compaction + desc, wave/graph, LDS-only atomics
    kr_build<<<NUM_GRAPHS_C / 4, 256, 0, stream>>>(esrc, edst, estart, rec, desc);
    // KM: fold (72) + slice-aligned node means (2048) + compacted edge gather (16384)
    km_mega <<<TOTAL_BLOCKS, 256, 0, stream>>>(
        h_node, nstart, desc, rec, W_node, W_edge, W1, nm, em8, Wc);
    // K3: fold partials + normalize + MLP
    k3_mlp  <<<NUM_GRAPHS_C / GPB, HDIM, 0, stream>>>(
        nm, em8, estart, Wc, b1, W2, b2, pred);
}